// Round 7
// baseline (95.629 us; speedup 1.0000x reference)
//
#include <hip/hip_runtime.h>
#include <hip/hip_fp16.h>
#include <stdint.h>

#define NB 256       // batch
#define NK 512       // in_features
#define NO 128       // out_features
#define NC 2048      // NO*KD
#define OUTW 640     // NK + NO
#define MAGIC 0x5A17C0DEu

typedef __attribute__((ext_vector_type(8))) short bf16x8;   // 8 bf16 (4 VGPRs)
typedef __attribute__((ext_vector_type(4))) float f32x4;
typedef __attribute__((ext_vector_type(4))) unsigned int u32x4;
typedef __attribute__((ext_vector_type(2))) unsigned int u32x2;

// pack 2 f32 -> 2 bf16 (truncation) in ONE v_perm_b32
__device__ __forceinline__ unsigned int pk(float lo, float hi) {
  return __builtin_amdgcn_perm(__builtin_bit_cast(unsigned int, hi),
                               __builtin_bit_cast(unsigned int, lo), 0x07060302u);
}

// ---------------------------------------------------------------------------
// Fused kernel, 1280 blocks (all co-resident: 24.6KB LDS -> 6/CU cap, need 5).
//   bid <  256 : GEMM producer (BM=32,BN=64,BK=128, single-buffered LDS,
//                fp16 mt epilogue); release-flag; exit.
//   bid >= 256 : pair consumer p=bid-256 -> (o=p>>3, bq=p&7); p<256 also
//                x-copies. POLLS THE 8 PRODUCER FLAGS WITH ATOMIC RMW
//                (fetch_add 0, agent scope): RMWs execute at the chip-level
//                coherence point, unlike round-5's relaxed loads which were
//                served stale from the consumer XCD's own L2 (~100us lag).
// Flags never reset: first call ordered (flags != MAGIC after 0xAA poison /
// initial state w.h.p.); replays may race benignly (mt bit-identical).
// ---------------------------------------------------------------------------
__global__ __launch_bounds__(256, 4) void k_fused(const float* __restrict__ x,
                                                  const float* __restrict__ T,
                                                  float* __restrict__ out,
                                                  __half* __restrict__ mt,
                                                  unsigned int* __restrict__ flag) {
  __shared__ alignas(16) unsigned char smem[24704];
  const int tid = threadIdx.x;
  const int bid = blockIdx.x;

  if (bid < 256) {
    // =================== GEMM producer ===================
    unsigned short* lds = (unsigned short*)smem;   // As[32*128] @0, Bs[64*128] @4096
    const int bn = (bid & 31) * 64;                // col base (c)
    const int bm = (bid >> 5) * 32;                // row base (a)
    const int lane = tid & 63, wid = tid >> 6;
    const int wr = wid >> 1, wc = wid & 1;         // wave -> 16 rows x 32 cols

    int arow[2], akg[2], bkb[2], bcb[2];
#pragma unroll
    for (int s = 0; s < 2; ++s) { int idx = tid + s * 256; arow[s] = idx >> 4; akg[s] = idx & 15; }
#pragma unroll
    for (int s = 0; s < 2; ++s) { int idx = tid + s * 256; bkb[s] = idx >> 4; bcb[s] = idx & 15; }

    f32x4 raf[2][2], rbf[2][4];
    auto loadG = [&](int t) {
#pragma unroll
      for (int s = 0; s < 2; ++s) {
        const float* p = x + (size_t)(bm + arow[s]) * NK + t * 128 + akg[s] * 8;
        raf[s][0] = *(const f32x4*)p;
        raf[s][1] = *(const f32x4*)(p + 4);
      }
#pragma unroll
      for (int s = 0; s < 2; ++s)
#pragma unroll
        for (int j = 0; j < 4; ++j)
          rbf[s][j] = *(const f32x4*)(T + (size_t)(t * 128 + bkb[s] * 4 + j) * NC + bn + bcb[s] * 4);
    };
    auto writeS = [&]() {
#pragma unroll
      for (int s = 0; s < 2; ++s) {                // A: k-contiguous pack, b128
        u32x4 w;
        w[0] = pk(raf[s][0][0], raf[s][0][1]);
        w[1] = pk(raf[s][0][2], raf[s][0][3]);
        w[2] = pk(raf[s][1][0], raf[s][1][1]);
        w[3] = pk(raf[s][1][2], raf[s][1][3]);
        *(u32x4*)(&lds[arow[s] * 128 + ((akg[s] ^ (arow[s] & 7)) << 3)]) = w;
      }
#pragma unroll
      for (int s = 0; s < 2; ++s) {                // B: in-reg transpose, b64
        const int kb = bkb[s], kg = kb >> 1, k0l = (kb & 1) * 4;
#pragma unroll
        for (int c = 0; c < 4; ++c) {
          u32x2 w;
          w[0] = pk(rbf[s][0][c], rbf[s][1][c]);
          w[1] = pk(rbf[s][2][c], rbf[s][3][c]);
          int bc = bcb[s] * 4 + c;
          *(u32x2*)(&lds[4096 + bc * 128 + ((kg ^ (bc & 7)) << 3) + k0l]) = w;
        }
      }
    };

    f32x4 acc[2] = {};
    const int rowA  = wr * 16 + (lane & 15);
    const int colB0 = wc * 32 + (lane & 15);

    loadG(0); writeS(); __syncthreads();
#pragma unroll
    for (int t = 0; t < 4; ++t) {
      if (t < 3) loadG(t + 1);                     // next-chunk loads under MFMA
#pragma unroll
      for (int ks = 0; ks < 4; ++ks) {
        int kg = ks * 4 + (lane >> 4);             // k-group of 8
        bf16x8 af = *(const bf16x8*)(&lds[rowA * 128 + ((kg ^ (rowA & 7)) << 3)]);
#pragma unroll
        for (int ct = 0; ct < 2; ++ct) {
          int col = colB0 + ct * 16;
          bf16x8 bv = *(const bf16x8*)(&lds[4096 + col * 128 + ((kg ^ (col & 7)) << 3)]);
          acc[ct] = __builtin_amdgcn_mfma_f32_16x16x32_bf16(af, bv, acc[ct], 0, 0, 0);
        }
      }
      if (t < 3) { __syncthreads(); writeS(); __syncthreads(); }
    }

    // C/D layout (verified): col = lane&15, row = (lane>>4)*4 + j; fp16 store
#pragma unroll
    for (int ct = 0; ct < 2; ++ct) {
      int colg = bn + wc * 32 + ct * 16 + (lane & 15);
      int o = colg >> 4, kd = colg & 15;
      int rbase = bm + wr * 16 + (lane >> 4) * 4;
#pragma unroll
      for (int j = 0; j < 4; ++j)
        mt[(size_t)o * 4096 + (size_t)(rbase + j) * 16 + kd] = __float2half(acc[ct][j]);
    }
    __syncthreads();                               // all waves' stores drained
    if (tid == 0)
      __hip_atomic_store(&flag[bid], MAGIC, __ATOMIC_RELEASE, __HIP_MEMORY_SCOPE_AGENT);
    return;
  }

  // =================== pair consumer ===================
  const int p = bid - 256;
  const int o = p >> 3, bq = p & 7;

  if (p < 256 && tid < 128) {                      // x-copy (independent work)
    int idx = p * 128 + tid;
    int row = idx >> 7, c4 = (idx & 127) * 4;
    *(f32x4*)(out + (size_t)row * OUTW + c4) = *(const f32x4*)(x + (size_t)row * NK + c4);
  }

  if (tid < 8) {                                   // 8 producers of col-block o>>2
    unsigned int* f = &flag[tid * 32 + (o >> 2)];
    // RMW poll: executes at the chip coherence point (not local-L2-cached)
    while (__hip_atomic_fetch_add(f, 0u, __ATOMIC_RELAXED, __HIP_MEMORY_SCOPE_AGENT) != MAGIC)
      __builtin_amdgcn_s_sleep(4);
  }
  __syncthreads();
  __threadfence();                                 // acquire: invalidate caches

  unsigned char* S = smem;                         // swizzled o-slice, 8KB
  float (*red)[33] = (float(*)[33])(smem + 8192);
  const __half* __restrict__ mo = mt + (size_t)o * 4096;

  // stage 8KB: 512 x 16B chunks, 2/thread (swizzle keeps writes <=2-way)
#pragma unroll
  for (int s = 0; s < 2; ++s) {
    int idx = tid + s * 256;
    int row = idx >> 1, h = idx & 1;
    u32x4 v = ((const u32x4*)mo)[idx];
    *(u32x4*)(&S[((row * 32) ^ (((row >> 2) & 3) << 5)) + h * 16]) = v;
  }
  __syncthreads();

  const int bg = tid & 7, aq = tid >> 3;
  const int wv = tid >> 6, aqr = aq & 7;
  const int r0 = bq * 32 + bg * 4;                 // this thread's 4 b-rows

  __half2 br[4][8];
#pragma unroll
  for (int r = 0; r < 4; ++r) {
    const __half2* pb = (const __half2*)&S[((r0 + r) * 32) ^ ((((r0 + r) >> 2) & 3) << 5)];
#pragma unroll
    for (int i = 0; i < 8; ++i) br[r][i] = pb[i];
  }

  float acc[4] = {0.f, 0.f, 0.f, 0.f};
#pragma unroll 2
  for (int it = 0; it < 8; ++it) {
    const int a = it * 32 + wv * 8 + aqr;          // 8-lane groups broadcast
    const __half2* pa = (const __half2*)&S[(a * 32) ^ (((a >> 2) & 3) << 5)];
    __half2 ra[8];
#pragma unroll
    for (int i = 0; i < 8; ++i) ra[i] = pa[i];
#pragma unroll
    for (int r = 0; r < 4; ++r) {
      __half2 s2 = __habs2(__hsub2(ra[0], br[r][0]));
#pragma unroll
      for (int i = 1; i < 8; ++i)
        s2 = __hadd2(s2, __habs2(__hsub2(ra[i], br[r][i])));
      float n = __low2float(s2) + __high2float(s2);
      acc[r] += __expf(-n);                        // 0 for a!=b (underflow), 1 self
    }
  }
#pragma unroll
  for (int r = 0; r < 4; ++r) red[aq][bg * 4 + r] = acc[r];
  __syncthreads();
  if (tid < 32) {
    float s = 0.f;
#pragma unroll
    for (int q = 0; q < 32; ++q) s += red[q][tid];
    out[(size_t)(bq * 32 + tid) * OUTW + NK + o] = s;
  }
}

// ---------------------------------------------------------------------------
extern "C" void kernel_launch(void* const* d_in, const int* in_sizes, int n_in,
                              void* d_out, int out_size, void* d_ws, size_t ws_size,
                              hipStream_t stream) {
  const float* x = (const float*)d_in[0];
  const float* T = (const float*)d_in[1];
  float* out = (float*)d_out;
  char* ws = (char*)d_ws;
  __half* mt = (__half*)ws;                                 // 1 MB
  unsigned int* flag = (unsigned int*)(ws + (2u << 20));    // 256 flags

  k_fused<<<1280, 256, 0, stream>>>(x, T, out, mt, flag);
}

// Round 8
// 21.266 us; speedup vs baseline: 4.4968x; 4.4968x over previous
//
#include <hip/hip_runtime.h>
#include <hip/hip_fp16.h>
#include <stdint.h>

#define NB 256       // batch
#define NK 512       // in_features
#define NO 128       // out_features
#define NC 2048      // NO*KD
#define OUTW 640     // NK + NO

typedef __attribute__((ext_vector_type(8))) short bf16x8;   // 8 bf16 (4 VGPRs)
typedef __attribute__((ext_vector_type(4))) float f32x4;
typedef __attribute__((ext_vector_type(4))) unsigned int u32x4;
typedef __attribute__((ext_vector_type(2))) unsigned int u32x2;

// pack 2 f32 -> 2 bf16 (truncation) in ONE v_perm_b32
__device__ __forceinline__ unsigned int pk(float lo, float hi) {
  return __builtin_amdgcn_perm(__builtin_bit_cast(unsigned int, hi),
                               __builtin_bit_cast(unsigned int, lo), 0x07060302u);
}
// byte offset of pair-layout row r (round-6-verified bank-set rotation)
__device__ __forceinline__ int swzrow(int r) {
  return (r * 32) ^ (((r >> 2) & 3) << 5);
}

// ---------------------------------------------------------------------------
// ONE kernel, NO cross-block dependency. grid 256 = (o 0..127) x (b-half),
// 512 threads (8 waves, 1 block/CU, 2 waves/SIMD).
// Phase 1: block recomputes its own o-slice GEMM (A[256x512] x B[512x16],
//          BK=64 in 8 chunks; 2x redundant across b-halves — 256 MFMA/block,
//          x re-reads served from per-XCD L2). Same verified swizzle/pack/
//          fragment machinery as rounds 1-6.
// Phase 2: epilogue writes acc straight into the fp16 pair-swizzled LDS
//          o-slice (no mt global round-trip), then the round-6-verified
//          packed-half2 pair phase: 128 b-rows x 256 a. x-copy folded in.
// ---------------------------------------------------------------------------
__global__ __launch_bounds__(512, 2) void k_one(const float* __restrict__ x,
                                                const float* __restrict__ T,
                                                float* __restrict__ out) {
  __shared__ alignas(16) unsigned char smem[34816];
  unsigned short* lds = (unsigned short*)smem;   // A[256][64] @elem 0, B[16][64] @elem 16384
  const int tid = threadIdx.x, bid = blockIdx.x;
  const int o = bid >> 1, hf = bid & 1;

  if (tid < 128) {                               // x-copy: 256 blocks * 128 f32x4
    int idx = bid * 128 + tid;
    int row = idx >> 7, c4 = (idx & 127) * 4;
    *(f32x4*)(out + (size_t)row * OUTW + c4) = *(const f32x4*)(x + (size_t)row * NK + c4);
  }

  // A staging: 256 rows x 8 kgroups(8) = 2048 slots, 4/thread
  int arow[4], akg[4];
#pragma unroll
  for (int s = 0; s < 4; ++s) { int idx = tid + s * 512; arow[s] = idx >> 3; akg[s] = idx & 7; }
  // B staging (tid<64): 16 kquads x 4 cquads micro-tiles (4k x 4c each)
  const int bkq = tid >> 2, bcq = tid & 3;

  f32x4 raf[4][2], rbf[4];
  auto loadG = [&](int t) {
#pragma unroll
    for (int s = 0; s < 4; ++s) {
      const float* p = x + (size_t)arow[s] * NK + t * 64 + akg[s] * 8;
      raf[s][0] = *(const f32x4*)p;
      raf[s][1] = *(const f32x4*)(p + 4);
    }
    if (tid < 64) {
#pragma unroll
      for (int j = 0; j < 4; ++j)
        rbf[j] = *(const f32x4*)(T + (size_t)(t * 64 + bkq * 4 + j) * NC + o * 16 + bcq * 4);
    }
  };
  auto writeS = [&]() {
#pragma unroll
    for (int s = 0; s < 4; ++s) {                // A: k-contiguous pack, b128
      u32x4 w;
      w[0] = pk(raf[s][0][0], raf[s][0][1]); w[1] = pk(raf[s][0][2], raf[s][0][3]);
      w[2] = pk(raf[s][1][0], raf[s][1][1]); w[3] = pk(raf[s][1][2], raf[s][1][3]);
      *(u32x4*)(&lds[arow[s] * 64 + ((akg[s] ^ (arow[s] & 7)) << 3)]) = w;
    }
    if (tid < 64) {                              // B: in-reg transpose, b64
#pragma unroll
      for (int c = 0; c < 4; ++c) {
        int cc = bcq * 4 + c;
        u32x2 w2;
        w2[0] = pk(rbf[0][c], rbf[1][c]);
        w2[1] = pk(rbf[2][c], rbf[3][c]);
        *(u32x2*)(&lds[16384 + cc * 64 + (((bkq >> 1) ^ (cc & 7)) << 3) + ((bkq & 1) << 2)]) = w2;
      }
    }
  };

  const int lane = tid & 63, wv = tid >> 6;      // 8 waves; wave rows wv*32..+31
  f32x4 acc[2] = {};
  loadG(0); writeS(); __syncthreads();
#pragma unroll
  for (int t = 0; t < 8; ++t) {
    if (t < 7) loadG(t + 1);                     // next-chunk loads under MFMA
#pragma unroll
    for (int ks = 0; ks < 2; ++ks) {
      int kg = ks * 4 + (lane >> 4);             // k-group of 8
      bf16x8 bv = *(const bf16x8*)(&lds[16384 + (lane & 15) * 64 + ((kg ^ (lane & 7)) << 3)]);
#pragma unroll
      for (int tl = 0; tl < 2; ++tl) {
        int row = wv * 32 + tl * 16 + (lane & 15);
        bf16x8 af = *(const bf16x8*)(&lds[row * 64 + ((kg ^ (row & 7)) << 3)]);
        acc[tl] = __builtin_amdgcn_mfma_f32_16x16x32_bf16(af, bv, acc[tl], 0, 0, 0);
      }
    }
    __syncthreads();                             // all frag reads done
    if (t < 7) { writeS(); __syncthreads(); }
  }

  // epilogue: acc -> fp16 pair-swizzled S (bytes 0..8191; A-stage is dead).
  // C/D layout (verified): col = lane&15, row = (lane>>4)*4 + j.
#pragma unroll
  for (int tl = 0; tl < 2; ++tl) {
    int c = lane & 15;
    int rb = wv * 32 + tl * 16 + (lane >> 4) * 4;
#pragma unroll
    for (int j = 0; j < 4; ++j)
      *(__half*)(&smem[swzrow(rb + j) + c * 2]) = __float2half(acc[tl][j]);
  }
  __syncthreads();

  // pair phase: o_b[b][o] = sum_a exp(-sum_kd |S[a]-S[b]|), this half's 128 b
  float* red = (float*)(smem + 8192);            // [16][128] f32 = 8KB
  const int bg = tid & 31, aq = tid >> 5;        // 32 b-groups(4 rows) x 16 a-groups
  const int r0 = hf * 128 + bg * 4;

  __half2 br[4][8];
#pragma unroll
  for (int r = 0; r < 4; ++r) {
    const __half2* pb = (const __half2*)(&smem[swzrow(r0 + r)]);
#pragma unroll
    for (int i = 0; i < 8; ++i) br[r][i] = pb[i];
  }
  float acp[4] = {0.f, 0.f, 0.f, 0.f};
#pragma unroll 2
  for (int it = 0; it < 16; ++it) {
    int a = aq * 16 + it;                        // uniform per 32-lane group
    const __half2* pa = (const __half2*)(&smem[swzrow(a)]);
    __half2 ra[8];
#pragma unroll
    for (int i = 0; i < 8; ++i) ra[i] = pa[i];
#pragma unroll
    for (int r = 0; r < 4; ++r) {
      __half2 s2 = __habs2(__hsub2(ra[0], br[r][0]));
#pragma unroll
      for (int i = 1; i < 8; ++i)
        s2 = __hadd2(s2, __habs2(__hsub2(ra[i], br[r][i])));
      float n = __low2float(s2) + __high2float(s2);
      acp[r] += __expf(-n);                      // 0 for a!=b (underflow), 1 self
    }
  }
#pragma unroll
  for (int r = 0; r < 4; ++r) red[aq * 128 + bg * 4 + r] = acp[r];
  __syncthreads();
  if (tid < 128) {
    float s = 0.f;
#pragma unroll
    for (int q = 0; q < 16; ++q) s += red[q * 128 + tid];
    out[(size_t)(hf * 128 + tid) * OUTW + NK + o] = s;
  }
}

// ---------------------------------------------------------------------------
extern "C" void kernel_launch(void* const* d_in, const int* in_sizes, int n_in,
                              void* d_out, int out_size, void* d_ws, size_t ws_size,
                              hipStream_t stream) {
  const float* x = (const float*)d_in[0];
  const float* T = (const float*)d_in[1];
  float* out = (float*)d_out;
  (void)d_ws; (void)ws_size;

  k_one<<<256, 512, 0, stream>>>(x, T, out);
}

// Round 9
// 19.575 us; speedup vs baseline: 4.8852x; 1.0864x over previous
//
#include <hip/hip_runtime.h>
#include <hip/hip_fp16.h>
#include <stdint.h>

#define NB 256       // batch
#define NK 512       // in_features
#define NO 128       // out_features
#define NC 2048      // NO*KD
#define OUTW 640     // NK + NO

typedef __attribute__((ext_vector_type(8))) short bf16x8;   // 8 bf16 (4 VGPRs)
typedef __attribute__((ext_vector_type(4))) float f32x4;
typedef __attribute__((ext_vector_type(4))) unsigned int u32x4;
typedef __attribute__((ext_vector_type(2))) unsigned int u32x2;

// pack 2 f32 -> 2 bf16 (truncation) in ONE v_perm_b32
__device__ __forceinline__ unsigned int pk(float lo, float hi) {
  return __builtin_amdgcn_perm(__builtin_bit_cast(unsigned int, hi),
                               __builtin_bit_cast(unsigned int, lo), 0x07060302u);
}
// byte offset of pair-layout row r (round-6-verified bank-set rotation)
__device__ __forceinline__ int swzrow(int r) {
  return (r * 32) ^ (((r >> 2) & 3) << 5);
}

// ---------------------------------------------------------------------------
// Kernel 1: mt[o][a][kd] = (half) sum_k x[a][k]*T[k][o*16+kd]
// BM=32, BN=32, BK=128; grid (64 N) x (8 M) = 512 blocks = 2 blocks/CU:
// two INDEPENDENT blocks per CU so one block's MFMA hides the other's
// barrier/vmcnt drain (m114 overlap — same-block waves share the barrier,
// separate blocks don't). Same verified swizzle/pack/fragment machinery
// as rounds 1-6, double-buffered LDS (32KB/block). x-copy folded in.
// ---------------------------------------------------------------------------
__global__ __launch_bounds__(256, 2) void k_gemm(const float* __restrict__ x,
                                                 const float* __restrict__ T,
                                                 float* __restrict__ out,
                                                 __half* __restrict__ mt) {
  __shared__ unsigned short lds[2][8192];   // As[32*128] @0, Bs[32*128] @4096 (elems)
  const int tid = threadIdx.x;
  const int bn = blockIdx.x * 32;           // col base (c)
  const int bm = blockIdx.y * 32;           // row base (a)
  const int lane = tid & 63, wid = tid >> 6;
  const int wr = wid >> 1, wc = wid & 1;    // wave -> 16 rows x 16 cols

  // x-copy to out (independent work): 512 blocks * 64 f32x4 = 32768
  {
    const int bid = blockIdx.y * 64 + blockIdx.x;
    if (tid < 64) {
      int idx = bid * 64 + tid;
      int row = idx >> 7, c4 = (idx & 127) * 4;
      *(f32x4*)(out + (size_t)row * OUTW + c4) = *(const f32x4*)(x + (size_t)row * NK + c4);
    }
  }

  // A staging: 32 rows x 16 kgroups(8) = 512 slots, 2/thread
  int arow[2], akg[2];
#pragma unroll
  for (int s = 0; s < 2; ++s) { int idx = tid + s * 256; arow[s] = idx >> 4; akg[s] = idx & 15; }
  // B staging: 32 kblk(4) x 8 cblk(4) = 256 micro-tiles, 1/thread
  const int bkb = tid >> 3, bcb = tid & 7;

  f32x4 raf[2][2], rbf[4];
  auto loadG = [&](int t) {
#pragma unroll
    for (int s = 0; s < 2; ++s) {
      const float* p = x + (size_t)(bm + arow[s]) * NK + t * 128 + akg[s] * 8;
      raf[s][0] = *(const f32x4*)p;
      raf[s][1] = *(const f32x4*)(p + 4);
    }
#pragma unroll
    for (int j = 0; j < 4; ++j)
      rbf[j] = *(const f32x4*)(T + (size_t)(t * 128 + bkb * 4 + j) * NC + bn + bcb * 4);
  };
  auto writeS = [&](int b) {
#pragma unroll
    for (int s = 0; s < 2; ++s) {           // A: k-contiguous pack, b128 write
      u32x4 w;
      w[0] = pk(raf[s][0][0], raf[s][0][1]);
      w[1] = pk(raf[s][0][2], raf[s][0][3]);
      w[2] = pk(raf[s][1][0], raf[s][1][1]);
      w[3] = pk(raf[s][1][2], raf[s][1][3]);
      *(u32x4*)(&lds[b][arow[s] * 128 + ((akg[s] ^ (arow[s] & 7)) << 3)]) = w;
    }
    {                                       // B: in-reg transpose, b64 writes
      const int kg = bkb >> 1, k0l = (bkb & 1) * 4;
#pragma unroll
      for (int c = 0; c < 4; ++c) {
        u32x2 w2;
        w2[0] = pk(rbf[0][c], rbf[1][c]);
        w2[1] = pk(rbf[2][c], rbf[3][c]);
        int cc = bcb * 4 + c;
        *(u32x2*)(&lds[b][4096 + cc * 128 + ((kg ^ (cc & 7)) << 3) + k0l]) = w2;
      }
    }
  };

  f32x4 acc = {};
  const int rowA = wr * 16 + (lane & 15);
  const int colB = wc * 16 + (lane & 15);

  loadG(0); writeS(0); __syncthreads();
#pragma unroll
  for (int t = 0; t < 4; ++t) {
    if (t < 3) loadG(t + 1);                // issue next-chunk loads early
    const int b = t & 1;
#pragma unroll
    for (int ks = 0; ks < 4; ++ks) {
      int kg = ks * 4 + (lane >> 4);        // k-group of 8
      bf16x8 af = *(const bf16x8*)(&lds[b][rowA * 128 + ((kg ^ (rowA & 7)) << 3)]);
      bf16x8 bv = *(const bf16x8*)(&lds[b][4096 + colB * 128 + ((kg ^ (colB & 7)) << 3)]);
      acc = __builtin_amdgcn_mfma_f32_16x16x32_bf16(af, bv, acc, 0, 0, 0);
    }
    if (t < 3) writeS((t + 1) & 1);         // pack+write under MFMA/load shadow
    __syncthreads();
  }

  // C/D layout (verified): col = lane&15, row = (lane>>4)*4 + j; fp16 store
  {
    int colg = bn + wc * 16 + (lane & 15);
    int o = colg >> 4, kd = colg & 15;      // 16-col tile == exactly one o
    int rbase = bm + wr * 16 + (lane >> 4) * 4;
#pragma unroll
    for (int j = 0; j < 4; ++j)
      mt[(size_t)o * 4096 + (size_t)(rbase + j) * 16 + kd] = __float2half(acc[j]);
  }
}

// ---------------------------------------------------------------------------
// Kernel 2: o_b[b][o] = sum_a exp(-sum_kd |mt[o][a][kd] - mt[o][b][kd]|)
// grid 2048 = (o, b-sixteenth), 6 blocks/CU (launch_bounds(256,6)) for TLP.
// 8 KB fp16 o-slice in LDS, round-6-verified bank-set-rotating row swizzle.
// 256 thr = 4 bg (4 b-rows each, in regs) x 64 aq (4 a's each).
// Reduction over aq: stride-4 shfl_down butterfly (no serial LDS-read tail).
// ---------------------------------------------------------------------------
__global__ __launch_bounds__(256, 6) void k_pair(const __half* __restrict__ mt,
                                                 float* __restrict__ out) {
  __shared__ unsigned char S[8192];         // swizzled o-slice: 256 rows * 32B
  __shared__ float red[4][16];              // [wave][local b-row]
  const int tid = threadIdx.x, bid = blockIdx.x;
  const int o = bid >> 4, bs = bid & 15;
  const __half* __restrict__ mo = mt + (size_t)o * 4096;

  // stage 8KB: 512 x 16B chunks, 2/thread (swizzle keeps writes <=2-way)
#pragma unroll
  for (int s = 0; s < 2; ++s) {
    int idx = tid + s * 256;
    int row = idx >> 1, h = idx & 1;
    u32x4 v = ((const u32x4*)mo)[idx];
    *(u32x4*)(&S[swzrow(row) + h * 16]) = v;
  }
  __syncthreads();

  const int bg = tid & 3, aq = tid >> 2;    // 4 b-groups x 64 a-groups
  const int lane = tid & 63, wv = tid >> 6;
  const int r0 = bs * 16 + bg * 4;          // this thread's 4 b-rows

  __half2 br[4][8];
#pragma unroll
  for (int r = 0; r < 4; ++r) {
    const __half2* pb = (const __half2*)(&S[swzrow(r0 + r)]);
#pragma unroll
    for (int i = 0; i < 8; ++i) br[r][i] = pb[i];
  }

  float acc[4] = {0.f, 0.f, 0.f, 0.f};
#pragma unroll
  for (int it = 0; it < 4; ++it) {
    const int a = aq * 4 + it;              // 16 distinct rows/wave: conflict-free
    const __half2* pa = (const __half2*)(&S[swzrow(a)]);
    __half2 ra[8];
#pragma unroll
    for (int i = 0; i < 8; ++i) ra[i] = pa[i];
#pragma unroll
    for (int r = 0; r < 4; ++r) {
      __half2 s2 = __habs2(__hsub2(ra[0], br[r][0]));
#pragma unroll
      for (int i = 1; i < 8; ++i)
        s2 = __hadd2(s2, __habs2(__hsub2(ra[i], br[r][i])));
      float n = __low2float(s2) + __high2float(s2);
      acc[r] += __expf(-n);                 // 0 for a!=b (underflow), 1 self
    }
  }
  // reduce over the 16 aq-groups within each wave: stride-4 butterfly
#pragma unroll
  for (int r = 0; r < 4; ++r) {
    acc[r] += __shfl_down(acc[r], 4);
    acc[r] += __shfl_down(acc[r], 8);
    acc[r] += __shfl_down(acc[r], 16);
    acc[r] += __shfl_down(acc[r], 32);
  }
  if (lane < 4) {
#pragma unroll
    for (int r = 0; r < 4; ++r) red[wv][lane * 4 + r] = acc[r];
  }
  __syncthreads();
  if (tid < 16) {                           // sum the 4 wave-partials
    float s = red[0][tid] + red[1][tid] + red[2][tid] + red[3][tid];
    out[(size_t)(bs * 16 + tid) * OUTW + NK + o] = s;
  }
}

// ---------------------------------------------------------------------------
extern "C" void kernel_launch(void* const* d_in, const int* in_sizes, int n_in,
                              void* d_out, int out_size, void* d_ws, size_t ws_size,
                              hipStream_t stream) {
  const float* x = (const float*)d_in[0];
  const float* T = (const float*)d_in[1];
  float* out = (float*)d_out;
  __half* mt = (__half*)d_ws;               // 1 MB scratch

  k_gemm<<<dim3(64, 8), 256, 0, stream>>>(x, T, out, mt);
  k_pair<<<2048, 256, 0, stream>>>(mt, out);
}

// Round 10
// 19.575 us; speedup vs baseline: 4.8852x; 1.0000x over previous
//
#include <hip/hip_runtime.h>
#include <hip/hip_fp16.h>
#include <stdint.h>

#define NB 256       // batch
#define NK 512       // in_features
#define NO 128       // out_features
#define NC 2048      // NO*KD
#define OUTW 640     // NK + NO

typedef __attribute__((ext_vector_type(8))) short bf16x8;   // 8 bf16 (4 VGPRs)
typedef __attribute__((ext_vector_type(4))) float f32x4;
typedef __attribute__((ext_vector_type(4))) unsigned int u32x4;
typedef __attribute__((ext_vector_type(2))) unsigned int u32x2;

// pack 2 f32 -> 2 bf16 (truncation) in ONE v_perm_b32
__device__ __forceinline__ unsigned int pk(float lo, float hi) {
  return __builtin_amdgcn_perm(__builtin_bit_cast(unsigned int, hi),
                               __builtin_bit_cast(unsigned int, lo), 0x07060302u);
}
// pair-phase LDS address of the h-th 16B chunk of row r.
// bits 5-6: bank-set rotation (round-6-verified); bit 4: 16B-half swap so
// a-broadcast groups (rows spaced 8) spread 4 slots -> 2-way (free, m136).
// Bijective (XOR of higher row bits into lower byte bits, within-slot).
__device__ __forceinline__ int swz16(int r, int h) {
  return (r * 32 + h * 16) ^ (((r >> 2) & 3) << 5) ^ (((r >> 4) & 1) << 4);
}

// ---------------------------------------------------------------------------
// Kernel 1: mt[o][a][kd] = (half) sum_k x[a][k]*T[k][o*16+kd]
// BM=32, BN=32, BK=128; grid (64 N) x (8 M) = 512 blocks = 2 blocks/CU
// (independent blocks hide each other's barrier/vmcnt drains, m114).
// Verified swizzle/pack/fragment machinery, double-buffered LDS. x-copy in.
// (unchanged from round 9)
// ---------------------------------------------------------------------------
__global__ __launch_bounds__(256, 2) void k_gemm(const float* __restrict__ x,
                                                 const float* __restrict__ T,
                                                 float* __restrict__ out,
                                                 __half* __restrict__ mt) {
  __shared__ unsigned short lds[2][8192];   // As[32*128] @0, Bs[32*128] @4096 (elems)
  const int tid = threadIdx.x;
  const int bn = blockIdx.x * 32;           // col base (c)
  const int bm = blockIdx.y * 32;           // row base (a)
  const int lane = tid & 63, wid = tid >> 6;
  const int wr = wid >> 1, wc = wid & 1;    // wave -> 16 rows x 16 cols

  // x-copy to out (independent work): 512 blocks * 64 f32x4 = 32768
  {
    const int bid = blockIdx.y * 64 + blockIdx.x;
    if (tid < 64) {
      int idx = bid * 64 + tid;
      int row = idx >> 7, c4 = (idx & 127) * 4;
      *(f32x4*)(out + (size_t)row * OUTW + c4) = *(const f32x4*)(x + (size_t)row * NK + c4);
    }
  }

  // A staging: 32 rows x 16 kgroups(8) = 512 slots, 2/thread
  int arow[2], akg[2];
#pragma unroll
  for (int s = 0; s < 2; ++s) { int idx = tid + s * 256; arow[s] = idx >> 4; akg[s] = idx & 15; }
  // B staging: 32 kblk(4) x 8 cblk(4) = 256 micro-tiles, 1/thread
  const int bkb = tid >> 3, bcb = tid & 7;

  f32x4 raf[2][2], rbf[4];
  auto loadG = [&](int t) {
#pragma unroll
    for (int s = 0; s < 2; ++s) {
      const float* p = x + (size_t)(bm + arow[s]) * NK + t * 128 + akg[s] * 8;
      raf[s][0] = *(const f32x4*)p;
      raf[s][1] = *(const f32x4*)(p + 4);
    }
#pragma unroll
    for (int j = 0; j < 4; ++j)
      rbf[j] = *(const f32x4*)(T + (size_t)(t * 128 + bkb * 4 + j) * NC + bn + bcb * 4);
  };
  auto writeS = [&](int b) {
#pragma unroll
    for (int s = 0; s < 2; ++s) {           // A: k-contiguous pack, b128 write
      u32x4 w;
      w[0] = pk(raf[s][0][0], raf[s][0][1]);
      w[1] = pk(raf[s][0][2], raf[s][0][3]);
      w[2] = pk(raf[s][1][0], raf[s][1][1]);
      w[3] = pk(raf[s][1][2], raf[s][1][3]);
      *(u32x4*)(&lds[b][arow[s] * 128 + ((akg[s] ^ (arow[s] & 7)) << 3)]) = w;
    }
    {                                       // B: in-reg transpose, b64 writes
      const int kg = bkb >> 1, k0l = (bkb & 1) * 4;
#pragma unroll
      for (int c = 0; c < 4; ++c) {
        u32x2 w2;
        w2[0] = pk(rbf[0][c], rbf[1][c]);
        w2[1] = pk(rbf[2][c], rbf[3][c]);
        int cc = bcb * 4 + c;
        *(u32x2*)(&lds[b][4096 + cc * 128 + ((kg ^ (cc & 7)) << 3) + k0l]) = w2;
      }
    }
  };

  f32x4 acc = {};
  const int rowA = wr * 16 + (lane & 15);
  const int colB = wc * 16 + (lane & 15);

  loadG(0); writeS(0); __syncthreads();
#pragma unroll
  for (int t = 0; t < 4; ++t) {
    if (t < 3) loadG(t + 1);                // issue next-chunk loads early
    const int b = t & 1;
#pragma unroll
    for (int ks = 0; ks < 4; ++ks) {
      int kg = ks * 4 + (lane >> 4);        // k-group of 8
      bf16x8 af = *(const bf16x8*)(&lds[b][rowA * 128 + ((kg ^ (rowA & 7)) << 3)]);
      bf16x8 bv = *(const bf16x8*)(&lds[b][4096 + colB * 128 + ((kg ^ (colB & 7)) << 3)]);
      acc = __builtin_amdgcn_mfma_f32_16x16x32_bf16(af, bv, acc, 0, 0, 0);
    }
    if (t < 3) writeS((t + 1) & 1);         // pack+write under MFMA/load shadow
    __syncthreads();
  }

  // C/D layout (verified): col = lane&15, row = (lane>>4)*4 + j; fp16 store
  {
    int colg = bn + wc * 16 + (lane & 15);
    int o = colg >> 4, kd = colg & 15;      // 16-col tile == exactly one o
    int rbase = bm + wr * 16 + (lane >> 4) * 4;
#pragma unroll
    for (int j = 0; j < 4; ++j)
      mt[(size_t)o * 4096 + (size_t)(rbase + j) * 16 + kd] = __float2half(acc[j]);
  }
}

// ---------------------------------------------------------------------------
// Kernel 2: o_b[b][o] = sum_a exp(-sum_kd |mt[o][a][kd] - mt[o][b][kd]|)
// grid 2048 = (o, b-sixteenth), launch_bounds(256,8) -> EXACT 8 blocks/CU
// residency (2048 = 8 x 256, zero dispatch tail, 32 waves/CU).
// 256 thr = 8 bg (2 b-rows each, br[2][8] = 8 VGPR -> fits 64-VGPR budget)
// x 32 aq (8 a's each). swz16 LDS layout: a-broadcast groups 2-way (free).
// Reduce: 3x shfl_down in-wave + 4-wave LDS hop.
// ---------------------------------------------------------------------------
__global__ __launch_bounds__(256, 8) void k_pair(const __half* __restrict__ mt,
                                                 float* __restrict__ out) {
  __shared__ unsigned char S[8192];         // swizzled o-slice: 256 rows * 32B
  __shared__ float red[4][16];              // [wave][local b-row]
  const int tid = threadIdx.x, bid = blockIdx.x;
  const int o = bid >> 4, bs = bid & 15;
  const __half* __restrict__ mo = mt + (size_t)o * 4096;

  // stage 8KB: 512 x 16B chunks, 2/thread
#pragma unroll
  for (int s = 0; s < 2; ++s) {
    int idx = tid + s * 256;
    u32x4 v = ((const u32x4*)mo)[idx];      // chunk = row (idx>>1), half (idx&1)
    *(u32x4*)(&S[swz16(idx >> 1, idx & 1)]) = v;
  }
  __syncthreads();

  const int bg = tid & 7, aq = tid >> 3;    // 8 b-groups x 32 a-groups
  const int lane = tid & 63, wv = tid >> 6;
  const int r0 = bs * 16 + bg * 2;          // this thread's 2 b-rows

  __half2 br[2][8];
#pragma unroll
  for (int r = 0; r < 2; ++r) {
    const __half2* p0 = (const __half2*)(&S[swz16(r0 + r, 0)]);
    const __half2* p1 = (const __half2*)(&S[swz16(r0 + r, 1)]);
#pragma unroll
    for (int i = 0; i < 4; ++i) { br[r][i] = p0[i]; br[r][4 + i] = p1[i]; }
  }

  float acc[2] = {0.f, 0.f};
#pragma unroll 2
  for (int it = 0; it < 8; ++it) {
    const int a = aq * 8 + it;              // groups spaced 8 rows: 2-way banks
    const __half2* p0 = (const __half2*)(&S[swz16(a, 0)]);
    const __half2* p1 = (const __half2*)(&S[swz16(a, 1)]);
    __half2 ra[8];
#pragma unroll
    for (int i = 0; i < 4; ++i) { ra[i] = p0[i]; ra[4 + i] = p1[i]; }
#pragma unroll
    for (int r = 0; r < 2; ++r) {
      __half2 s2 = __habs2(__hsub2(ra[0], br[r][0]));
#pragma unroll
      for (int i = 1; i < 8; ++i)
        s2 = __hadd2(s2, __habs2(__hsub2(ra[i], br[r][i])));
      float n = __low2float(s2) + __high2float(s2);
      acc[r] += __expf(-n);                 // 0 for a!=b (underflow), 1 self
    }
  }
  // reduce over the 8 aq-groups within each wave (stride-8 lanes)
#pragma unroll
  for (int r = 0; r < 2; ++r) {
    acc[r] += __shfl_down(acc[r], 8);
    acc[r] += __shfl_down(acc[r], 16);
    acc[r] += __shfl_down(acc[r], 32);
  }
  if (lane < 8) {
    red[wv][bg * 2 + 0] = acc[0];
    red[wv][bg * 2 + 1] = acc[1];
  }
  __syncthreads();
  if (tid < 16) {                           // sum the 4 wave-partials
    float s = red[0][tid] + red[1][tid] + red[2][tid] + red[3][tid];
    out[(size_t)(bs * 16 + tid) * OUTW + NK + o] = s;
  }
}

// ---------------------------------------------------------------------------
extern "C" void kernel_launch(void* const* d_in, const int* in_sizes, int n_in,
                              void* d_out, int out_size, void* d_ws, size_t ws_size,
                              hipStream_t stream) {
  const float* x = (const float*)d_in[0];
  const float* T = (const float*)d_in[1];
  float* out = (float*)d_out;
  __half* mt = (__half*)d_ws;               // 1 MB scratch

  k_gemm<<<dim3(64, 8), 256, 0, stream>>>(x, T, out, mt);
  k_pair<<<2048, 256, 0, stream>>>(mt, out);
}